// Round 2
// baseline (173.788 us; speedup 1.0000x reference)
//
#include <hip/hip_runtime.h>
#include <hip/hip_bf16.h>
#include <stdint.h>

// QuantizedLinearFSDP: out[m][n] = sum_k x[m][k] * W[n][k] + bias[n]
//   W[n][g*128+s] = codebooks[n][g][codes[n][g][s]]
// M=2048, N=4096, K=4096, G=32, S=128, B=16.
//
// R7: fat register tiles to break the LDS-read bound. R5/R6's 4x4 frag
// blocking gave 64 int-ops per LDS byte -> ds_read_b128 (~85 B/cy) was the
// binding pipe (MfmaUtil 30%). Now: BM=256 x BN=128 block, 8 waves with
// k-pair split, each wave owns 128x64 (RM=8 x RN=4 frags) -> 32 MFMAs per
// 12 KB LDS = 85 ops/B -> MFMA pipe becomes binding (floor ~16 us).
// Grid 32x8 = 256 blocks = 1/CU; LDS 96 KB double-buffered (2-phase
// counted-vmcnt(6) pipeline from R6, verified); same XOR chunk swizzle
// (all row offsets ===0 mod 8 so sc/fs formulas carry over unchanged);
// k-pair reduction vectorized to b128. i8 math identical -> bit-identical
// output vs R5/R6.
// Prepass unchanged from R5 (verified).

#define M_DIM 2048
#define N_DIM 4096
#define K_DIM 4096

typedef __attribute__((ext_vector_type(4))) int i32x4;

__device__ __forceinline__ void async_load16(const void* g, void* l) {
    __builtin_amdgcn_global_load_lds(
        (const __attribute__((address_space(1))) uint32_t*)(uintptr_t)g,
        (__attribute__((address_space(3))) uint32_t*)(uint32_t)(uintptr_t)l,
        16, 0, 0);
}

__device__ __forceinline__ uint32_t pack4(int a, int b, int c, int d) {
    return (uint32_t)(a & 255) | ((uint32_t)(b & 255) << 8) |
           ((uint32_t)(c & 255) << 16) | ((uint32_t)(d & 255) << 24);
}

__device__ __forceinline__ int q8(float v, float inv) {
    return (int)rintf(v * inv);   // RNE, |v*inv| <= 127 by construction
}

// ---------------- pre-pass: quantize W and x to i8 + per-row scales -------
// blocks [0, 4096): W row o. Stage 512 cb floats in LDS, absmax -> scale,
//   quantize 4096 codes (16/thread) to i8, write as dwords.
// blocks [4096, 6144): x row m. absmax over 4096 floats -> scale, quantize.
__global__ __launch_bounds__(256) void prepass_q8(
    const float* __restrict__ cb,      // [4096][32][16]
    const int* __restrict__ codes,     // [4096][32][128]
    const float* __restrict__ x,       // [2048][4096]
    uint32_t* __restrict__ wq,         // [4096][1024] dwords (i8x4)
    uint32_t* __restrict__ xq,         // [2048][1024] dwords (i8x4)
    float* __restrict__ sw,            // [4096]
    float* __restrict__ sx)            // [2048]
{
    __shared__ float scb[512];
    __shared__ float red[256];
    const int b = blockIdx.x, t = threadIdx.x;
    if (b < N_DIM) {
        const int o = b;
        const float c0 = cb[(size_t)o * 512 + t];
        const float c1 = cb[(size_t)o * 512 + 256 + t];
        scb[t] = c0; scb[t + 256] = c1;
        red[t] = fmaxf(fabsf(c0), fabsf(c1));
        __syncthreads();
        for (int s = 128; s > 0; s >>= 1) {
            if (t < s) red[t] = fmaxf(red[t], red[t + s]);
            __syncthreads();
        }
        const float amax = fmaxf(red[0], 1e-20f);
        const float inv = 127.0f / amax;
        if (t == 0) sw[o] = amax / 127.0f;
        const int* crow = codes + (size_t)o * K_DIM;
        uint32_t* orow = wq + (size_t)o * 1024;
#pragma unroll
        for (int i = 0; i < 4; ++i) {
            const int d = t + i * 256;                 // dword index 0..1023
            const int4 c = *(const int4*)(crow + d * 4);
            const float* g = scb + (d >> 5) * 16;      // group = (4d)>>7
            orow[d] = pack4(q8(g[c.x], inv), q8(g[c.y], inv),
                            q8(g[c.z], inv), q8(g[c.w], inv));
        }
    } else {
        const int m = b - N_DIM;
        const float* row = x + (size_t)m * K_DIM;
        float4 v[4];
        float am = 0.f;
#pragma unroll
        for (int i = 0; i < 4; ++i) {
            v[i] = *(const float4*)(row + (size_t)(t + i * 256) * 4);
            am = fmaxf(am, fmaxf(fmaxf(fabsf(v[i].x), fabsf(v[i].y)),
                                 fmaxf(fabsf(v[i].z), fabsf(v[i].w))));
        }
        red[t] = am;
        __syncthreads();
        for (int s = 128; s > 0; s >>= 1) {
            if (t < s) red[t] = fmaxf(red[t], red[t + s]);
            __syncthreads();
        }
        const float amax = fmaxf(red[0], 1e-20f);
        const float inv = 127.0f / amax;
        if (t == 0) sx[m] = amax / 127.0f;
        uint32_t* orow = xq + (size_t)m * 1024;
#pragma unroll
        for (int i = 0; i < 4; ++i)
            orow[t + i * 256] = pack4(q8(v[i].x, inv), q8(v[i].y, inv),
                                      q8(v[i].z, inv), q8(v[i].w, inv));
    }
}

// ---------------- main GEMM (i8): C = A*B^T scaled + bias ----------------
// A [2048][4096] i8, B [4096][4096] i8, C f32. BM=256 x BN=128 tile,
// BK=128, 512 threads = 8 waves: wk=w>>2 (k-half), wm=((w>>1)&1)*128,
// wn=(w&1)*64. Each wave: RM=8 x RN=4 of 16x16x64 frags = 128x64 output
// over its 64-k half; k-pair LDS reduction at the end (verified R5).
// LDS: double-buffered As [256][128] (32KB) + Bs [128][128] (16KB) = 96KB.
// Row = 128B = 8 x 16B chunks; slot s of row r holds global k-chunk
// s ^ (r&7) -> 2-way banks only (0 conflicts verified on this swizzle).

__device__ __forceinline__ void compute_tile(
    const unsigned char* As, const unsigned char* Bs,
    const int wm, const int wn, const int l15, const int fs,
    i32x4 acc[8][4])
{
    i32x4 af[8], bf[4];
#pragma unroll
    for (int i = 0; i < 8; ++i)
        af[i] = *(const i32x4*)(As + (wm + i * 16 + l15) * 128 + fs);
#pragma unroll
    for (int i = 0; i < 4; ++i)
        bf[i] = *(const i32x4*)(Bs + (wn + i * 16 + l15) * 128 + fs);
#pragma unroll
    for (int mi = 0; mi < 8; ++mi)
#pragma unroll
        for (int ni = 0; ni < 4; ++ni)
            acc[mi][ni] = __builtin_amdgcn_mfma_i32_16x16x64_i8(
                af[mi], bf[ni], acc[mi][ni], 0, 0, 0);
}

__global__ __launch_bounds__(512, 2) void gemm_i8(
    const unsigned char* __restrict__ A,
    const unsigned char* __restrict__ B,
    const float* __restrict__ sx,
    const float* __restrict__ sw,
    const float* __restrict__ bias,
    float* __restrict__ C)
{
    __shared__ __align__(16) unsigned char smem[98304];
    unsigned char* As0 = smem;               // [256][128] i8, buffer 0
    unsigned char* Bs0 = smem + 32768;       // [128][128] i8
    unsigned char* As1 = smem + 49152;       // buffer 1
    unsigned char* Bs1 = smem + 81920;

    const int tid  = threadIdx.x;
    const int w    = tid >> 6;        // wave 0..7
    const int lane = tid & 63;
    const int l15  = lane & 15;
    const int quad = lane >> 4;
    const int m0   = blockIdx.y * 256;
    const int n0   = blockIdx.x * 128;
    const int wk   = w >> 2;          // k-half 0/1
    const int wm   = ((w >> 1) & 1) * 128;
    const int wn   = (w & 1) * 64;

    // staging: per call, wave w / lane l covers row (w*8 + l>>3) of a
    // 64-row group, slot l&7 holding global k-chunk (l&7)^(l>>3)
    // (row&7 == l>>3 since w*8 and the 64-row group offsets are ===0 mod 8).
    const int r8 = lane >> 3;                        // 0..7
    const int sc = (lane & 7) ^ r8;                  // global k-chunk
    const unsigned char* gA = A + (size_t)(m0 + w * 8 + r8) * K_DIM + sc * 16;
    const unsigned char* gB = B + (size_t)(n0 + w * 8 + r8) * K_DIM + sc * 16;

    // frag reads: row = wm/wn + i*16 + l15 -> row&7 == l15&7. Wave's wanted
    // chunk = wk*4 + quad -> slot = chunk ^ (l15&7). Byte offset in row:
    const int fs = (((wk << 2) + quad) ^ (l15 & 7)) * 16;

    auto stage = [&](unsigned char* As, unsigned char* Bs, int k) {
        // A: 256 rows = 4 x 64-row groups; B: 128 rows = 2 groups.
        async_load16(gA + k,                        As +         w * 1024);
        async_load16(gA + k + (size_t)64  * K_DIM,  As + 8192  + w * 1024);
        async_load16(gA + k + (size_t)128 * K_DIM,  As + 16384 + w * 1024);
        async_load16(gA + k + (size_t)192 * K_DIM,  As + 24576 + w * 1024);
        async_load16(gB + k,                        Bs +         w * 1024);
        async_load16(gB + k + (size_t)64  * K_DIM,  Bs + 8192  + w * 1024);
    };

    i32x4 acc[8][4] = {};

    stage(As0, Bs0, 0);                    // prologue: tile 0 -> buf0
    for (int k0 = 0; k0 < K_DIM; k0 += 256) {
        // ---- phase A: prefetch buf1 <- k0+128, compute buf0 (k0) ----
        stage(As1, Bs1, k0 + 128);
        asm volatile("s_waitcnt vmcnt(6)" ::: "memory");  // buf0 loads done
        __builtin_amdgcn_s_barrier();
        asm volatile("" ::: "memory");     // keep ds_reads below barrier
        compute_tile(As0, Bs0, wm, wn, l15, fs, acc);
        asm volatile("s_waitcnt lgkmcnt(0)" ::: "memory");
        __builtin_amdgcn_sched_barrier(0); // no sink past this point
        __builtin_amdgcn_s_barrier();      // all reads of buf0 done

        // ---- phase B: prefetch buf0 <- k0+256, compute buf1 (k0+128) ----
        if (k0 + 256 < K_DIM) {
            stage(As0, Bs0, k0 + 256);
            asm volatile("s_waitcnt vmcnt(6)" ::: "memory");  // buf1 done
        } else {
            asm volatile("s_waitcnt vmcnt(0)" ::: "memory");  // drain
        }
        __builtin_amdgcn_s_barrier();
        asm volatile("" ::: "memory");
        compute_tile(As1, Bs1, wm, wn, l15, fs, acc);
        asm volatile("s_waitcnt lgkmcnt(0)" ::: "memory");
        __builtin_amdgcn_sched_barrier(0);
        __builtin_amdgcn_s_barrier();      // all reads of buf1 done
    }

    // ---- k-pair reduction: wave w (wk=0) += wave w+4 (wk=1), via LDS ----
    // Layout: vec slot (mi*4+ni)*64 + lane -> lane's i32x4 contiguous
    // (b128 writes/reads, fully sequential per wave -> conflict-free).
    // 2 waves at a time: 2 x 32 KB = 64 KB <= 96 KB smem.
    i32x4* red = (i32x4*)smem;
    if (w == 4 || w == 5) {
        i32x4* dst = red + (w & 1) * 2048;
#pragma unroll
        for (int mi = 0; mi < 8; ++mi)
#pragma unroll
            for (int ni = 0; ni < 4; ++ni)
                dst[(mi * 4 + ni) * 64 + lane] = acc[mi][ni];
    }
    __syncthreads();
    if (w == 0 || w == 1) {
        const i32x4* src = red + (w & 1) * 2048;
#pragma unroll
        for (int mi = 0; mi < 8; ++mi)
#pragma unroll
            for (int ni = 0; ni < 4; ++ni) {
                const i32x4 v = src[(mi * 4 + ni) * 64 + lane];
                acc[mi][ni] = acc[mi][ni] + v;
            }
    }
    __syncthreads();
    if (w == 6 || w == 7) {
        i32x4* dst = red + (w & 1) * 2048;
#pragma unroll
        for (int mi = 0; mi < 8; ++mi)
#pragma unroll
            for (int ni = 0; ni < 4; ++ni)
                dst[(mi * 4 + ni) * 64 + lane] = acc[mi][ni];
    }
    __syncthreads();
    if (w == 2 || w == 3) {
        const i32x4* src = red + (w & 1) * 2048;
#pragma unroll
        for (int mi = 0; mi < 8; ++mi)
#pragma unroll
            for (int ni = 0; ni < 4; ++ni) {
                const i32x4 v = src[(mi * 4 + ni) * 64 + lane];
                acc[mi][ni] = acc[mi][ni] + v;
            }
    }

    // ---- epilogue (waves 0..3): C/D col = lane&15, row = quad*4+reg ----
    if (w < 4) {
        float swv[4], bv[4];
#pragma unroll
        for (int ni = 0; ni < 4; ++ni) {
            const int col = n0 + wn + ni * 16 + l15;
            swv[ni] = sw[col];
            bv[ni]  = bias[col];
        }
#pragma unroll
        for (int mi = 0; mi < 8; ++mi) {
            float sxr[4];
#pragma unroll
            for (int r = 0; r < 4; ++r)
                sxr[r] = sx[m0 + wm + mi * 16 + quad * 4 + r];
#pragma unroll
            for (int ni = 0; ni < 4; ++ni) {
                const int col = n0 + wn + ni * 16 + l15;
                float* cp = C + (size_t)(m0 + wm + mi * 16 + quad * 4) * N_DIM + col;
#pragma unroll
                for (int r = 0; r < 4; ++r)
                    cp[(size_t)r * N_DIM] =
                        (float)acc[mi][ni][r] * (sxr[r] * swv[ni]) + bv[ni];
            }
        }
    }
}

// ---------------- fallback (ws too small): naive fp32 ----------------
__global__ __launch_bounds__(256) void naive_kernel(
    const float* __restrict__ x, const float* __restrict__ cb,
    const int* __restrict__ codes, const float* __restrict__ bias,
    float* __restrict__ out)
{
    const size_t idx = (size_t)blockIdx.x * 256 + threadIdx.x;  // m*4096 + n
    const int n = (int)(idx & 4095);
    const int m = (int)(idx >> 12);
    const float* xr = x + (size_t)m * K_DIM;
    float s = bias[n];
    for (int g = 0; g < 32; ++g) {
        const float* cbr = cb + ((size_t)n * 32 + g) * 16;
        const int* cr = codes + ((size_t)n * 32 + g) * 128;
        const float* xg = xr + g * 128;
        for (int ss = 0; ss < 128; ++ss) s += xg[ss] * cbr[cr[ss]];
    }
    out[idx] = s;
}

extern "C" void kernel_launch(void* const* d_in, const int* in_sizes, int n_in,
                              void* d_out, int out_size, void* d_ws, size_t ws_size,
                              hipStream_t stream) {
    const float* x     = (const float*)d_in[0];   // [2,1024,4096] f32
    const float* cb    = (const float*)d_in[1];   // [4096,32,16]  f32
    const int*   codes = (const int*)d_in[2];     // [4096,32,128] i32
    const float* bias  = (const float*)d_in[3];   // [4096]        f32
    float* out = (float*)d_out;                   // [2,1024,4096] f32

    const size_t szW = (size_t)N_DIM * K_DIM;          // 16.78 MB i8
    const size_t szX = (size_t)M_DIM * K_DIM;          // 8.39 MB i8
    const size_t need = szW + szX + (N_DIM + M_DIM) * sizeof(float);

    if (ws_size >= need) {
        unsigned char* Wq = (unsigned char*)d_ws;
        unsigned char* Xq = Wq + szW;
        float* sw = (float*)(Xq + szX);
        float* sx = sw + N_DIM;
        prepass_q8<<<dim3(N_DIM + M_DIM), dim3(256), 0, stream>>>(
            cb, codes, x, (uint32_t*)Wq, (uint32_t*)Xq, sw, sx);
        gemm_i8<<<dim3(N_DIM / 128, M_DIM / 256), dim3(512), 0, stream>>>(
            Xq, Wq, sx, sw, bias, out);
    } else {
        naive_kernel<<<dim3((M_DIM * N_DIM) / 256), dim3(256), 0, stream>>>(x, cb, codes, bias, out);
    }
}